// Round 16
// baseline (92.493 us; speedup 1.0000x reference)
//
#include <hip/hip_runtime.h>
#include <math.h>

// Problem constants (from reference setup_inputs)
constexpr int B = 8, N = 2048, H = 512, M = 96, S = 16;
constexpr int E = 256, D = 64, R = 5, MAXD = 600;
constexpr int NZ = 32;            // n-splits for sent max partial
constexpr int NCHUNK = N / NZ;    // 64
constexpr int MT = 8;             // mentions per gemm block
constexpr int HC = 4;             // h-chunks
constexpr int HCH = H / HC;       // 128
constexpr int MT4 = 8;            // m-rows per final-max tile
constexpr int RS = 2 * B * M;     // dotp row-stride (1536 rows)
constexpr float NEG_INF = -1e10f;

constexpr int G_GEMM = 2 * B * (M / MT) * HC;   // 768
constexpr int G_SENT = B * NZ / 2;              // 128
constexpr int G_DIST = MAXD / 4;                // 150
constexpr int P1_ITEMS = G_GEMM + G_SENT + G_DIST;   // 1046

constexpr int G3_PROJ = RS / 4;                 // 384
constexpr int P2_ITEMS = G3_PROJ + B;           // 392
constexpr int P3_ITEMS = (M / MT4) * B;         // 96
constexpr int G34 = P2_ITEMS + P3_ITEMS;        // 488 (co-resident worst case 512)

__device__ inline void atomicMaxFloat(float* addr, float val) {
    int* ai = (int*)addr;
    int old = *ai;
    while (__int_as_float(old) < val) {
        int assumed = old;
        old = atomicCAS(ai, assumed, __float_as_int(val));
        if (old == assumed) break;
    }
}

// ===========================================================================
// Phase bodies (identical to round 12 — proven)
// ===========================================================================
__device__ __forceinline__ void p1_body(
        int item, int t,
        const float* __restrict__ node,
        const int* __restrict__ cmap, const float* __restrict__ cmask,
        const int* __restrict__ dmap, const float* __restrict__ dmask,
        const float* __restrict__ Wc, const float* __restrict__ Wd,
        const float* __restrict__ Wsc, const float* __restrict__ emb,
        float* __restrict__ part, float* __restrict__ dotp,
        float* __restrict__ validAB, float* __restrict__ sD,
        int smap[MT][S], float smask[MT][S], float lp[MT][HCH]) {
    if (item < G_GEMM) {
        int hc   = item & 3;
        int rest = item >> 2;
        int mg = rest % (M / MT);
        int b  = (rest / (M / MT)) % B;
        int z  = rest / ((M / MT) * B);
        const float* W    = z ? Wd : Wc;
        const int*   map  = z ? dmap  : cmap;
        const float* mask = z ? dmask : cmask;

        if (t < MT * S) {
            int mi = t >> 4, s = t & 15;
            size_t off = ((size_t)b * M + mg * MT + mi) * S + s;
            smap[mi][s]  = map[off];
            smask[mi][s] = mask[off];
        }
        __syncthreads();

        {
            int mi = t >> 5, slot = t & 31;
            float4 a = make_float4(0.f, 0.f, 0.f, 0.f);
            #pragma unroll
            for (int s = 0; s < S; ++s) {
                float mk = smask[mi][s];
                const float4 v = reinterpret_cast<const float4*>(
                    node + ((size_t)b * N + smap[mi][s]) * H + hc * HCH)[slot];
                a.x += mk * v.x; a.y += mk * v.y;
                a.z += mk * v.z; a.w += mk * v.w;
            }
            reinterpret_cast<float4*>(&lp[mi][0])[slot] = a;
        }
        if (hc == 0 && t < MT) {
            float ms = 0.f;
            #pragma unroll
            for (int s = 0; s < S; ++s) ms += smask[t][s];
            validAB[((size_t)z * B + b) * M + mg * MT + t] = (ms > 0.f) ? 1.f : 0.f;
        }
        __syncthreads();

        float acc[MT] = {};
        const float* Wp = W + (size_t)(hc * HCH) * E + t;
        #pragma unroll 4
        for (int hh = 0; hh < HCH; hh += 4) {
            float w0 = Wp[(size_t)(hh + 0) * E];
            float w1 = Wp[(size_t)(hh + 1) * E];
            float w2 = Wp[(size_t)(hh + 2) * E];
            float w3 = Wp[(size_t)(hh + 3) * E];
            #pragma unroll
            for (int mi = 0; mi < MT; ++mi) {
                const float4 pv = *reinterpret_cast<const float4*>(&lp[mi][hh]);
                acc[mi] += pv.x * w0 + pv.y * w1 + pv.z * w2 + pv.w * w3;
            }
        }
        #pragma unroll
        for (int mi = 0; mi < MT; ++mi) {
            size_t row = ((size_t)z * B + b) * M + mg * MT + mi;
            dotp[((size_t)hc * RS + row) * E + t] = acc[mi];
        }
    } else if (item < G_GEMM + G_SENT) {
        int sb = item - G_GEMM;
        int b = sb >> 4;
        int z = ((sb & 15) << 1) + (t >> 7);
        int tt = t & 127;
        const float4* p = reinterpret_cast<const float4*>(
            node + ((size_t)b * N + (size_t)z * NCHUNK) * H) + tt;
        float4 mx = p[0];
        #pragma unroll 8
        for (int n = 1; n < NCHUNK; ++n) {
            float4 v = p[(size_t)n * (H / 4)];
            mx.x = fmaxf(mx.x, v.x); mx.y = fmaxf(mx.y, v.y);
            mx.z = fmaxf(mx.z, v.z); mx.w = fmaxf(mx.w, v.w);
        }
        reinterpret_cast<float4*>(part + ((size_t)z * B + b) * H)[tt] = mx;
    } else {
        int d = (item - G_GEMM - G_SENT) * 4 + (t >> 6);
        int k = t & 63;
        float v = emb[(size_t)d * D + k];
        #pragma unroll
        for (int r = 0; r < R; ++r) {
            float p = v * Wsc[(size_t)(2 * E + k) * R + r];
            for (int off = 32; off; off >>= 1) p += __shfl_down(p, off, 64);
            if (k == 0) sD[d * R + r] = p;
        }
    }
}

__device__ __forceinline__ void p2_body(
        int item, int t,
        const float* __restrict__ dotp,
        const float* __restrict__ bc, const float* __restrict__ bd,
        const float* __restrict__ Wsc, const float* __restrict__ bsc,
        const float* __restrict__ part,
        float* __restrict__ sAB, float* __restrict__ sS,
        float sent[H], float red[R][4]) {
    const int wave = t >> 6, lane = t & 63;
    if (item < G3_PROJ) {
        int rid = item * 4 + wave;
        int z = rid / (B * M);
        const float* bias = z ? bd : bc;
        int scoff = z ? E : 0;

        float4 dv = reinterpret_cast<const float4*>(bias)[lane];
        #pragma unroll
        for (int hc = 0; hc < HC; ++hc) {
            const float4 v = reinterpret_cast<const float4*>(
                dotp + ((size_t)hc * RS + rid) * E)[lane];
            dv.x += v.x; dv.y += v.y; dv.z += v.z; dv.w += v.w;
        }
        float v0 = tanhf(dv.x), v1 = tanhf(dv.y), v2 = tanhf(dv.z), v3 = tanhf(dv.w);

        int e0 = scoff + 4 * lane;
        float p[R];
        #pragma unroll
        for (int r = 0; r < R; ++r) {
            p[r] = v0 * Wsc[(size_t)(e0 + 0) * R + r] + v1 * Wsc[(size_t)(e0 + 1) * R + r]
                 + v2 * Wsc[(size_t)(e0 + 2) * R + r] + v3 * Wsc[(size_t)(e0 + 3) * R + r];
        }
        #pragma unroll
        for (int r = 0; r < R; ++r) {
            for (int off = 32; off; off >>= 1) p[r] += __shfl_down(p[r], off, 64);
        }
        if (lane == 0) {
            #pragma unroll
            for (int r = 0; r < R; ++r) sAB[(size_t)rid * R + r] = p[r];
        }
    } else {
        int b = item - G3_PROJ;
        for (int h = t; h < H; h += 256) {
            float mx = -INFINITY;
            #pragma unroll 8
            for (int z = 0; z < NZ; ++z) mx = fmaxf(mx, part[((size_t)z * B + b) * H + h]);
            sent[h] = mx;
        }
        __syncthreads();
        float acc[R] = {};
        for (int h = t; h < H; h += 256) {
            float v = sent[h];
            const float* w = Wsc + (size_t)(2 * E + D + h) * R;
            #pragma unroll
            for (int r = 0; r < R; ++r) acc[r] += v * w[r];
        }
        #pragma unroll
        for (int r = 0; r < R; ++r) {
            float v = acc[r];
            for (int off = 32; off; off >>= 1) v += __shfl_down(v, off, 64);
            if (lane == 0) red[r][wave] = v;
        }
        __syncthreads();
        if (t < R) sS[b * R + t] = red[t][0] + red[t][1] + red[t][2] + red[t][3] + bsc[t];
    }
}

__device__ __forceinline__ void p3_body(
        int item, int t,
        const int* __restrict__ distance,
        const float* __restrict__ sAB, const float* __restrict__ validAB,
        const float* __restrict__ sD, const float* __restrict__ sS,
        float* __restrict__ out,
        float lB[M * R], float lD[MAXD * R], float lA[MT4 * R],
        float lvA[MT4], float lvB[M], float red[R][4]) {
    const int g = item % (M / MT4);
    const int b = item / (M / MT4);
    const int wave = t >> 6, lane = t & 63;

    for (int i = t; i < M * R; i += 256) lB[i] = sAB[((size_t)(B + b)) * M * R + i];
    for (int i = t; i < MAXD * R; i += 256) lD[i] = sD[i];
    if (t < MT4 * R) lA[t] = sAB[((size_t)b * M + g * MT4) * R + t] + sS[b * R + (t % R)];
    if (t < MT4) lvA[t] = validAB[(size_t)b * M + g * MT4 + t];
    for (int i = t; i < M; i += 256) lvB[i] = validAB[((size_t)B + b) * M + i];
    __syncthreads();

    float mx[R];
    #pragma unroll
    for (int r = 0; r < R; ++r) mx[r] = NEG_INF;

    #pragma unroll
    for (int it = 0; it < (MT4 * M) / 256; ++it) {
        int idx = it * 256 + t;
        int mi = idx / M, n = idx % M;
        int dist = distance[((size_t)b * M + g * MT4 + mi) * M + n];
        if (lvA[mi] > 0.f && lvB[n] > 0.f && dist >= 0 /*DIST_THRESH*/) {
            #pragma unroll
            for (int r = 0; r < R; ++r)
                mx[r] = fmaxf(mx[r], lA[mi * R + r] + lB[n * R + r] + lD[dist * R + r]);
        }
    }
    #pragma unroll
    for (int r = 0; r < R; ++r) {
        float v = mx[r];
        for (int off = 32; off; off >>= 1) v = fmaxf(v, __shfl_down(v, off, 64));
        if (lane == 0) red[r][wave] = v;
    }
    __syncthreads();
    if (t < R) {
        float v = fmaxf(fmaxf(red[t][0], red[t][1]), fmaxf(red[t][2], red[t][3]));
        atomicMaxFloat(out + b * R + t, v);
    }
}

// ===========================================================================
// k1: round-12 kernel 1 (proven).  Also zeroes the done-flag and inits out.
// ===========================================================================
__global__ __launch_bounds__(256)
void k1(const float* __restrict__ node,
        const int* __restrict__ cmap, const float* __restrict__ cmask,
        const int* __restrict__ dmap, const float* __restrict__ dmask,
        const float* __restrict__ Wc, const float* __restrict__ Wd,
        const float* __restrict__ Wsc, const float* __restrict__ emb,
        float* __restrict__ part, float* __restrict__ dotp,
        float* __restrict__ validAB, float* __restrict__ sD,
        float* __restrict__ out, int* __restrict__ done) {
    __shared__ int   smap[MT][S];
    __shared__ float smask[MT][S];
    __shared__ float lp[MT][HCH];
    if (blockIdx.x == 0) {
        if (threadIdx.x < B * R) out[threadIdx.x] = NEG_INF;
        if (threadIdx.x == 0)
            __hip_atomic_store(done, 0, __ATOMIC_RELEASE, __HIP_MEMORY_SCOPE_AGENT);
    }
    p1_body(blockIdx.x, threadIdx.x, node, cmap, cmask, dmap, dmask, Wc, Wd, Wsc, emb,
            part, dotp, validAB, sD, smap, smask, lp);
}

// ===========================================================================
// k34: fused proj/sS (producers, blocks [0,392)) + pair-max (consumers,
// blocks [392,488)). Consumers poll with ACQUIRE LOADS (no RMW ping-pong);
// producers signal once with a RELEASE fetch_add. 488 blocks co-resident.
// ===========================================================================
__global__ __launch_bounds__(256)
void k34(const float* __restrict__ dotp,
         const float* __restrict__ bc, const float* __restrict__ bd,
         const float* __restrict__ Wsc, const float* __restrict__ bsc,
         const float* __restrict__ part,
         const int* __restrict__ distance, const float* __restrict__ validAB,
         const float* __restrict__ sD,
         float* __restrict__ sAB, float* __restrict__ sS,
         float* __restrict__ out, int* __restrict__ done) {
    const int blk = blockIdx.x;
    const int t = threadIdx.x;

    __shared__ float sent[H];          // 2 KB   (producer)
    __shared__ float red[R][4];
    __shared__ float lB[M * R];        // 1.9 KB (consumer)
    __shared__ float lD[MAXD * R];     // 12 KB
    __shared__ float lA[MT4 * R];
    __shared__ float lvA[MT4], lvB[M];

    if (blk < P2_ITEMS) {
        p2_body(blk, t, dotp, bc, bd, Wsc, bsc, part, sAB, sS, sent, red);
        __syncthreads();               // all block stores complete
        __threadfence();               // flush to device scope
        if (t == 0)
            __hip_atomic_fetch_add(done, 1, __ATOMIC_RELEASE, __HIP_MEMORY_SCOPE_AGENT);
    } else {
        if (t == 0) {
            // poll with loads, not RMWs — no exclusive-ownership ping-pong
            while (__hip_atomic_load(done, __ATOMIC_ACQUIRE, __HIP_MEMORY_SCOPE_AGENT)
                   < P2_ITEMS) {
                __builtin_amdgcn_s_sleep(32);
            }
        }
        __syncthreads();
        __threadfence();               // acquire-side ordering before reads
        p3_body(blk - P2_ITEMS, t, distance, sAB, validAB, sD, sS, out,
                lB, lD, lA, lvA, lvB, red);
    }
}

// ---------------------------------------------------------------------------
extern "C" void kernel_launch(void* const* d_in, const int* in_sizes, int n_in,
                              void* d_out, int out_size, void* d_ws, size_t ws_size,
                              hipStream_t stream) {
    const float* node     = (const float*)d_in[0];
    const int*   cmap     = (const int*)  d_in[1];
    const float* cmask    = (const float*)d_in[2];
    const int*   dmap     = (const int*)  d_in[3];
    const float* dmask    = (const float*)d_in[4];
    const int*   distance = (const int*)  d_in[5];
    const float* Wc       = (const float*)d_in[6];
    const float* bc       = (const float*)d_in[7];
    const float* Wd       = (const float*)d_in[8];
    const float* bd       = (const float*)d_in[9];
    const float* Wsc      = (const float*)d_in[10];
    const float* bsc      = (const float*)d_in[11];
    const float* emb      = (const float*)d_in[12];
    float* out = (float*)d_out;

    // workspace layout (floats): total ~7 MB
    float* ws      = (float*)d_ws;
    float* part    = ws;                             // NZ*B*H      = 131072
    float* validAB = part + (size_t)NZ * B * H;      // 2*B*M       = 1536
    float* sD      = validAB + 2 * B * M;            // MAXD*R      = 3000
    float* sS      = sD + MAXD * R;                  // B*R         = 40
    float* sAB     = sS + B * R;                     // RS*R        = 7680
    float* dotp    = sAB + (size_t)RS * R;           // HC*RS*E     = 1572864
    int*   done    = (int*)(dotp + (size_t)HC * RS * E);

    hipLaunchKernelGGL(k1, dim3(P1_ITEMS), dim3(256), 0, stream,
                       node, cmap, cmask, dmap, dmask, Wc, Wd, Wsc, emb,
                       part, dotp, validAB, sD, out, done);
    hipLaunchKernelGGL(k34, dim3(G34), dim3(256), 0, stream,
                       dotp, bc, bd, Wsc, bsc, part, distance, validAB, sD,
                       sAB, sS, out, done);
}

// Round 17
// 68.675 us; speedup vs baseline: 1.3468x; 1.3468x over previous
//
#include <hip/hip_runtime.h>
#include <math.h>

// Problem constants (from reference setup_inputs)
constexpr int B = 8, N = 2048, H = 512, M = 96, S = 16;
constexpr int E = 256, D = 64, R = 5, MAXD = 600;
constexpr int NZ = 32;            // n-splits for sent max partial
constexpr int NCHUNK = N / NZ;    // 64
constexpr int MT = 8;             // mentions per gemm block
constexpr int HC = 4;             // h-chunks
constexpr int HCH = H / HC;       // 128
constexpr int MT4 = 8;            // m-rows per final-max tile
constexpr int RS = 2 * B * M;     // dotp row-stride (1536 rows)
constexpr float NEG_INF = -1e10f;

constexpr int G_GEMM = 2 * B * (M / MT) * HC;   // 768
constexpr int G_SENT = B * NZ / 2;              // 128
constexpr int G_DIST = MAXD / 4;                // 150
constexpr int G1 = G_GEMM + G_SENT + G_DIST;    // 1046

__device__ inline void atomicMaxFloat(float* addr, float val) {
    int* ai = (int*)addr;
    int old = *ai;
    while (__int_as_float(old) < val) {
        int assumed = old;
        old = atomicCAS(ai, assumed, __float_as_int(val));
        if (old == assumed) break;
    }
}

// ===========================================================================
// k1: IDENTICAL to round-12 kernel 1 (proven). pool-slice+partial-GEMM |
//     sent-partial | dist table | out init
// ===========================================================================
__global__ __launch_bounds__(256)
void k1(const float* __restrict__ node,
        const int* __restrict__ cmap, const float* __restrict__ cmask,
        const int* __restrict__ dmap, const float* __restrict__ dmask,
        const float* __restrict__ Wc, const float* __restrict__ Wd,
        const float* __restrict__ Wsc, const float* __restrict__ emb,
        float* __restrict__ part, float* __restrict__ dotp,
        float* __restrict__ validAB, float* __restrict__ sD,
        float* __restrict__ out) {
    const int blk = blockIdx.x;
    const int t = threadIdx.x;

    if (blk == 0 && t < B * R) out[t] = NEG_INF;   // init for kW's atomicMax

    if (blk < G_GEMM) {
        int hc   = blk & 3;
        int rest = blk >> 2;
        int mg = rest % (M / MT);
        int b  = (rest / (M / MT)) % B;
        int z  = rest / ((M / MT) * B);
        const float* W    = z ? Wd : Wc;
        const int*   map  = z ? dmap  : cmap;
        const float* mask = z ? dmask : cmask;

        __shared__ int   smap[MT][S];
        __shared__ float smask[MT][S];
        __shared__ float lp[MT][HCH];      // 4 KB

        if (t < MT * S) {
            int mi = t >> 4, s = t & 15;
            size_t off = ((size_t)b * M + mg * MT + mi) * S + s;
            smap[mi][s]  = map[off];
            smask[mi][s] = mask[off];
        }
        __syncthreads();

        {
            int mi = t >> 5, slot = t & 31;
            float4 a = make_float4(0.f, 0.f, 0.f, 0.f);
            #pragma unroll
            for (int s = 0; s < S; ++s) {
                float mk = smask[mi][s];
                const float4 v = reinterpret_cast<const float4*>(
                    node + ((size_t)b * N + smap[mi][s]) * H + hc * HCH)[slot];
                a.x += mk * v.x; a.y += mk * v.y;
                a.z += mk * v.z; a.w += mk * v.w;
            }
            reinterpret_cast<float4*>(&lp[mi][0])[slot] = a;
        }
        if (hc == 0 && t < MT) {
            float ms = 0.f;
            #pragma unroll
            for (int s = 0; s < S; ++s) ms += smask[t][s];
            validAB[((size_t)z * B + b) * M + mg * MT + t] = (ms > 0.f) ? 1.f : 0.f;
        }
        __syncthreads();

        float acc[MT] = {};
        const float* Wp = W + (size_t)(hc * HCH) * E + t;
        #pragma unroll 4
        for (int hh = 0; hh < HCH; hh += 4) {
            float w0 = Wp[(size_t)(hh + 0) * E];
            float w1 = Wp[(size_t)(hh + 1) * E];
            float w2 = Wp[(size_t)(hh + 2) * E];
            float w3 = Wp[(size_t)(hh + 3) * E];
            #pragma unroll
            for (int mi = 0; mi < MT; ++mi) {
                const float4 pv = *reinterpret_cast<const float4*>(&lp[mi][hh]);
                acc[mi] += pv.x * w0 + pv.y * w1 + pv.z * w2 + pv.w * w3;
            }
        }
        #pragma unroll
        for (int mi = 0; mi < MT; ++mi) {
            size_t row = ((size_t)z * B + b) * M + mg * MT + mi;
            dotp[((size_t)hc * RS + row) * E + t] = acc[mi];
        }
    } else if (blk < G_GEMM + G_SENT) {
        int sb = blk - G_GEMM;
        int b = sb >> 4;
        int z = ((sb & 15) << 1) + (t >> 7);
        int tt = t & 127;
        const float4* p = reinterpret_cast<const float4*>(
            node + ((size_t)b * N + (size_t)z * NCHUNK) * H) + tt;
        float4 mx = p[0];
        #pragma unroll 8
        for (int n = 1; n < NCHUNK; ++n) {
            float4 v = p[(size_t)n * (H / 4)];
            mx.x = fmaxf(mx.x, v.x); mx.y = fmaxf(mx.y, v.y);
            mx.z = fmaxf(mx.z, v.z); mx.w = fmaxf(mx.w, v.w);
        }
        reinterpret_cast<float4*>(part + ((size_t)z * B + b) * H)[tt] = mx;
    } else {
        int d = (blk - G_GEMM - G_SENT) * 4 + (t >> 6);
        int k = t & 63;
        float v = emb[(size_t)d * D + k];
        #pragma unroll
        for (int r = 0; r < R; ++r) {
            float p = v * Wsc[(size_t)(2 * E + k) * R + r];
            for (int off = 32; off; off >>= 1) p += __shfl_down(p, off, 64);
            if (k == 0) sD[d * R + r] = p;
        }
    }
}

// ===========================================================================
// kW: per (b, 8-m tile): sent+sS | recompute lA (8 rows) and lB (96 rows)
//     from dotp with batched prefetch | pair max | atomicMax.
// grid 96, block 256 (4 waves).
// ===========================================================================
__global__ __launch_bounds__(256)
void kW(const float* __restrict__ part, const float* __restrict__ Wsc,
        const float* __restrict__ bsc,
        const float* __restrict__ bc, const float* __restrict__ bd,
        const int* __restrict__ distance,
        const float* __restrict__ dotp, const float* __restrict__ validAB,
        const float* __restrict__ sD, float* __restrict__ out) {
    const int g = blockIdx.x % (M / MT4);
    const int b = blockIdx.x / (M / MT4);
    const int t = threadIdx.x;
    const int wave = t >> 6, lane = t & 63;

    __shared__ float sent[H];          // 2 KB
    __shared__ float red[R][4];
    __shared__ float sSb[R];
    __shared__ float lA[MT4 * R];
    __shared__ float lB[M * R];        // 1.9 KB
    __shared__ float lD[MAXD * R];     // 12 KB
    __shared__ float lvA[MT4], lvB[M];

    const float4* dotp4 = reinterpret_cast<const float4*>(dotp);

    // ---- stage lD early (independent of everything) ----
    for (int i = t; i < MAXD * R; i += 256) lD[i] = sD[i];
    if (t < MT4) lvA[t] = validAB[(size_t)b * M + g * MT4 + t];
    for (int i = t; i < M; i += 256) lvB[i] = validAB[((size_t)B + b) * M + i];

    // ---- sent max + sS ----
    for (int h = t; h < H; h += 256) {
        float mx = -INFINITY;
        #pragma unroll 8
        for (int z = 0; z < NZ; ++z) mx = fmaxf(mx, part[((size_t)z * B + b) * H + h]);
        sent[h] = mx;
    }
    __syncthreads();
    {
        float acc[R] = {};
        for (int h = t; h < H; h += 256) {
            float v = sent[h];
            const float* w = Wsc + (size_t)(2 * E + D + h) * R;
            #pragma unroll
            for (int r = 0; r < R; ++r) acc[r] += v * w[r];
        }
        #pragma unroll
        for (int r = 0; r < R; ++r) {
            float v = acc[r];
            for (int off = 32; off; off >>= 1) v += __shfl_down(v, off, 64);
            if (lane == 0) red[r][wave] = v;
        }
        __syncthreads();
        if (t < R) sSb[t] = red[t][0] + red[t][1] + red[t][2] + red[t][3] + bsc[t];
        __syncthreads();
    }

    // per-lane projection weights: chem (e0c) and dis (e0d)
    const int e0c = 4 * lane;
    const int e0d = E + 4 * lane;
    const float4 bc4 = reinterpret_cast<const float4*>(bc)[lane];
    const float4 bd4 = reinterpret_cast<const float4*>(bd)[lane];

    // ---- lA: 8 chem rows, wave w -> rows w and w+4 ----
    #pragma unroll
    for (int half = 0; half < 2; ++half) {
        int mi = wave + half * 4;
        size_t row = (size_t)b * M + g * MT4 + mi;        // z = 0
        float4 dv = bc4;
        #pragma unroll
        for (int hc = 0; hc < HC; ++hc) {
            float4 v = dotp4[((size_t)hc * RS + row) * (E / 4) + lane];
            dv.x += v.x; dv.y += v.y; dv.z += v.z; dv.w += v.w;
        }
        float v0 = tanhf(dv.x), v1 = tanhf(dv.y), v2 = tanhf(dv.z), v3 = tanhf(dv.w);
        float p[R];
        #pragma unroll
        for (int r = 0; r < R; ++r) {
            p[r] = v0 * Wsc[(size_t)(e0c + 0) * R + r] + v1 * Wsc[(size_t)(e0c + 1) * R + r]
                 + v2 * Wsc[(size_t)(e0c + 2) * R + r] + v3 * Wsc[(size_t)(e0c + 3) * R + r];
        }
        #pragma unroll
        for (int r = 0; r < R; ++r) {
            for (int off = 32; off; off >>= 1) p[r] += __shfl_down(p[r], off, 64);
        }
        if (lane == 0) {
            #pragma unroll
            for (int r = 0; r < R; ++r) lA[mi * R + r] = p[r] + sSb[r];
        }
    }

    // ---- lB: 96 dis rows, wave w -> rows [w*24, w*24+24), 6 batches of 4
    //      batched prefetch: 16 independent float4 loads per batch per lane ----
    for (int bt = 0; bt < 6; ++bt) {
        int n_base = wave * 24 + bt * 4;
        float4 v[4][HC];
        #pragma unroll
        for (int j = 0; j < 4; ++j) {
            size_t row = (size_t)(B + b) * M + (n_base + j);   // z = 1
            #pragma unroll
            for (int hc = 0; hc < HC; ++hc)
                v[j][hc] = dotp4[((size_t)hc * RS + row) * (E / 4) + lane];
        }
        #pragma unroll
        for (int j = 0; j < 4; ++j) {
            float4 dv = bd4;
            #pragma unroll
            for (int hc = 0; hc < HC; ++hc) {
                dv.x += v[j][hc].x; dv.y += v[j][hc].y;
                dv.z += v[j][hc].z; dv.w += v[j][hc].w;
            }
            float v0 = tanhf(dv.x), v1 = tanhf(dv.y), v2 = tanhf(dv.z), v3 = tanhf(dv.w);
            float p[R];
            #pragma unroll
            for (int r = 0; r < R; ++r) {
                p[r] = v0 * Wsc[(size_t)(e0d + 0) * R + r] + v1 * Wsc[(size_t)(e0d + 1) * R + r]
                     + v2 * Wsc[(size_t)(e0d + 2) * R + r] + v3 * Wsc[(size_t)(e0d + 3) * R + r];
            }
            #pragma unroll
            for (int r = 0; r < R; ++r) {
                for (int off = 32; off; off >>= 1) p[r] += __shfl_down(p[r], off, 64);
            }
            if (lane == 0) {
                #pragma unroll
                for (int r = 0; r < R; ++r) lB[(n_base + j) * R + r] = p[r];
            }
        }
    }
    __syncthreads();

    // ---- pair max over 8 x 96 ----
    float mx[R];
    #pragma unroll
    for (int r = 0; r < R; ++r) mx[r] = NEG_INF;

    #pragma unroll
    for (int it = 0; it < (MT4 * M) / 256; ++it) {
        int idx = it * 256 + t;           // [0, 768)
        int mi = idx / M, n = idx % M;
        int dist = distance[((size_t)b * M + g * MT4 + mi) * M + n];
        if (lvA[mi] > 0.f && lvB[n] > 0.f && dist >= 0 /*DIST_THRESH*/) {
            #pragma unroll
            for (int r = 0; r < R; ++r)
                mx[r] = fmaxf(mx[r], lA[mi * R + r] + lB[n * R + r] + lD[dist * R + r]);
        }
    }
    #pragma unroll
    for (int r = 0; r < R; ++r) {
        float v = mx[r];
        for (int off = 32; off; off >>= 1) v = fmaxf(v, __shfl_down(v, off, 64));
        if (lane == 0) red[r][wave] = v;
    }
    __syncthreads();
    if (t < R) {
        float v = fmaxf(fmaxf(red[t][0], red[t][1]), fmaxf(red[t][2], red[t][3]));
        atomicMaxFloat(out + b * R + t, v);
    }
}

// ---------------------------------------------------------------------------
extern "C" void kernel_launch(void* const* d_in, const int* in_sizes, int n_in,
                              void* d_out, int out_size, void* d_ws, size_t ws_size,
                              hipStream_t stream) {
    const float* node     = (const float*)d_in[0];
    const int*   cmap     = (const int*)  d_in[1];
    const float* cmask    = (const float*)d_in[2];
    const int*   dmap     = (const int*)  d_in[3];
    const float* dmask    = (const float*)d_in[4];
    const int*   distance = (const int*)  d_in[5];
    const float* Wc       = (const float*)d_in[6];
    const float* bc       = (const float*)d_in[7];
    const float* Wd       = (const float*)d_in[8];
    const float* bd       = (const float*)d_in[9];
    const float* Wsc      = (const float*)d_in[10];
    const float* bsc      = (const float*)d_in[11];
    const float* emb      = (const float*)d_in[12];
    float* out = (float*)d_out;

    // workspace layout (floats): total ~7 MB
    float* ws      = (float*)d_ws;
    float* part    = ws;                             // NZ*B*H      = 131072
    float* validAB = part + (size_t)NZ * B * H;      // 2*B*M       = 1536
    float* sD      = validAB + 2 * B * M;            // MAXD*R      = 3000
    float* dotp    = sD + MAXD * R;                  // HC*RS*E     = 1572864

    hipLaunchKernelGGL(k1, dim3(G1), dim3(256), 0, stream,
                       node, cmap, cmask, dmap, dmask, Wc, Wd, Wsc, emb,
                       part, dotp, validAB, sD, out);
    hipLaunchKernelGGL(kW, dim3((M / MT4) * B), dim3(256), 0, stream,
                       part, Wsc, bsc, bc, bd, distance, dotp, validAB, sD, out);
}

// Round 18
// 57.922 us; speedup vs baseline: 1.5968x; 1.1856x over previous
//
#include <hip/hip_runtime.h>
#include <math.h>

// Problem constants (from reference setup_inputs)
constexpr int B = 8, N = 2048, H = 512, M = 96, S = 16;
constexpr int E = 256, D = 64, R = 5, MAXD = 600;
constexpr int NZ = 32;            // n-splits for sent max partial
constexpr int NCHUNK = N / NZ;    // 64
constexpr int MT = 12;            // mentions per gemm block (96/12 = 8 groups)
constexpr int HC = 4;             // h-chunks
constexpr int HCH = H / HC;       // 128
constexpr int MT4 = 8;            // m-rows per final-max tile
constexpr int RS = 2 * B * M;     // dotp row-stride (1536 rows)
constexpr float NEG_INF = -1e10f;

constexpr int G_GEMM = 2 * B * (M / MT) * HC;   // 512 = exactly 2 blocks/CU
constexpr int G_SENT = B * NZ / 2;              // 128
constexpr int G_DIST = MAXD / 4;                // 150
constexpr int G1 = G_GEMM + G_SENT + G_DIST;    // 790

constexpr int G3_PROJ = RS / 4;                 // 384 tanh+proj blocks (4 rows each)
constexpr int G3 = G3_PROJ + B;                 // + 8 sS blocks

__device__ inline void atomicMaxFloat(float* addr, float val) {
    int* ai = (int*)addr;
    int old = *ai;
    while (__int_as_float(old) < val) {
        int assumed = old;
        old = atomicCAS(ai, assumed, __float_as_int(val));
        if (old == assumed) break;
    }
}

// ===========================================================================
// k1: pool-slice+partial-GEMM (MT=12) | sent-partial | dist table | out init
// ===========================================================================
__global__ __launch_bounds__(256)
void k1(const float* __restrict__ node,
        const int* __restrict__ cmap, const float* __restrict__ cmask,
        const int* __restrict__ dmap, const float* __restrict__ dmask,
        const float* __restrict__ Wc, const float* __restrict__ Wd,
        const float* __restrict__ Wsc, const float* __restrict__ emb,
        float* __restrict__ part, float* __restrict__ dotp,
        float* __restrict__ validAB, float* __restrict__ sD,
        float* __restrict__ out) {
    const int blk = blockIdx.x;
    const int t = threadIdx.x;

    if (blk == 0 && t < B * R) out[t] = NEG_INF;   // init for k4's atomicMax

    if (blk < G_GEMM) {
        // block = (z, b, mg, hc): pool h-slice for 12 mentions, partial GEMM
        int hc   = blk & 3;
        int rest = blk >> 2;
        int mg = rest % (M / MT);
        int b  = (rest / (M / MT)) % B;
        int z  = rest / ((M / MT) * B);
        const float* W    = z ? Wd : Wc;
        const int*   map  = z ? dmap  : cmap;
        const float* mask = z ? dmask : cmask;

        __shared__ int   smap[MT][S];
        __shared__ float smask[MT][S];
        __shared__ float lp[MT][HCH];      // 6 KB

        if (t < MT * S) {                  // 192 <= 256
            int mi = t >> 4, s = t & 15;
            size_t off = ((size_t)b * M + mg * MT + mi) * S + s;
            smap[mi][s]  = map[off];
            smask[mi][s] = mask[off];
        }
        __syncthreads();

        // pool slice: item = (mention, float4-slot of 128-h slice), 384 items
        for (int item = t; item < MT * 32; item += 256) {
            int mi = item >> 5, slot = item & 31;
            float4 a = make_float4(0.f, 0.f, 0.f, 0.f);
            #pragma unroll
            for (int s = 0; s < S; ++s) {
                float mk = smask[mi][s];
                const float4 v = reinterpret_cast<const float4*>(
                    node + ((size_t)b * N + smap[mi][s]) * H + hc * HCH)[slot];
                a.x += mk * v.x; a.y += mk * v.y;
                a.z += mk * v.z; a.w += mk * v.w;
            }
            reinterpret_cast<float4*>(&lp[mi][0])[slot] = a;
        }
        if (hc == 0 && t < MT) {
            float ms = 0.f;
            #pragma unroll
            for (int s = 0; s < S; ++s) ms += smask[t][s];
            validAB[((size_t)z * B + b) * M + mg * MT + t] = (ms > 0.f) ? 1.f : 0.f;
        }
        __syncthreads();

        // partial GEMM: thread = e; W rows coalesced across threads
        float acc[MT] = {};
        const float* Wp = W + (size_t)(hc * HCH) * E + t;
        #pragma unroll 4
        for (int hh = 0; hh < HCH; hh += 4) {
            float w0 = Wp[(size_t)(hh + 0) * E];
            float w1 = Wp[(size_t)(hh + 1) * E];
            float w2 = Wp[(size_t)(hh + 2) * E];
            float w3 = Wp[(size_t)(hh + 3) * E];
            #pragma unroll
            for (int mi = 0; mi < MT; ++mi) {
                const float4 pv = *reinterpret_cast<const float4*>(&lp[mi][hh]);
                acc[mi] += pv.x * w0 + pv.y * w1 + pv.z * w2 + pv.w * w3;
            }
        }
        #pragma unroll
        for (int mi = 0; mi < MT; ++mi) {
            size_t row = ((size_t)z * B + b) * M + mg * MT + mi;
            dotp[((size_t)hc * RS + row) * E + t] = acc[mi];
        }
    } else if (blk < G_GEMM + G_SENT) {
        // sent partial max: block = (b, 2 z-chunks); z-chunk = 64 tokens
        int sb = blk - G_GEMM;
        int b = sb >> 4;
        int z = ((sb & 15) << 1) + (t >> 7);
        int tt = t & 127;   // float4 index over H
        const float4* p = reinterpret_cast<const float4*>(
            node + ((size_t)b * N + (size_t)z * NCHUNK) * H) + tt;
        float4 mx = p[0];
        #pragma unroll 8
        for (int n = 1; n < NCHUNK; ++n) {
            float4 v = p[(size_t)n * (H / 4)];
            mx.x = fmaxf(mx.x, v.x); mx.y = fmaxf(mx.y, v.y);
            mx.z = fmaxf(mx.z, v.z); mx.w = fmaxf(mx.w, v.w);
        }
        reinterpret_cast<float4*>(part + ((size_t)z * B + b) * H)[tt] = mx;
    } else {
        // distance table: 4 distances per block, one wave each
        int d = (blk - G_GEMM - G_SENT) * 4 + (t >> 6);
        int k = t & 63;
        float v = emb[(size_t)d * D + k];
        #pragma unroll
        for (int r = 0; r < R; ++r) {
            float p = v * Wsc[(size_t)(2 * E + k) * R + r];
            for (int off = 32; off; off >>= 1) p += __shfl_down(p, off, 64);
            if (k == 0) sD[d * R + r] = p;
        }
    }
}

// ===========================================================================
// k3: tanh+proj per entity row (blocks [0,384), wave = row) | sent sS ([384,392))
// (byte-identical to round 12 — proven)
// ===========================================================================
__global__ __launch_bounds__(256)
void k3(const float* __restrict__ dotp,
        const float* __restrict__ bc, const float* __restrict__ bd,
        const float* __restrict__ Wsc, const float* __restrict__ bsc,
        const float* __restrict__ part,
        float* __restrict__ sAB, float* __restrict__ sS) {
    const int blk = blockIdx.x;
    const int t = threadIdx.x;
    const int wave = t >> 6, lane = t & 63;

    if (blk < G3_PROJ) {
        int rid = blk * 4 + wave;            // entity row in [0, 1536)
        int z = rid / (B * M);
        const float* bias = z ? bd : bc;
        int scoff = z ? E : 0;

        // sum 4 h-chunk partials + bias (float4 over E, lane = e-quad)
        float4 dv = reinterpret_cast<const float4*>(bias)[lane];
        #pragma unroll
        for (int hc = 0; hc < HC; ++hc) {
            const float4 v = reinterpret_cast<const float4*>(
                dotp + ((size_t)hc * RS + rid) * E)[lane];
            dv.x += v.x; dv.y += v.y; dv.z += v.z; dv.w += v.w;
        }
        float v0 = tanhf(dv.x), v1 = tanhf(dv.y), v2 = tanhf(dv.z), v3 = tanhf(dv.w);

        int e0 = scoff + 4 * lane;
        float p[R];
        #pragma unroll
        for (int r = 0; r < R; ++r) {
            p[r] = v0 * Wsc[(size_t)(e0 + 0) * R + r] + v1 * Wsc[(size_t)(e0 + 1) * R + r]
                 + v2 * Wsc[(size_t)(e0 + 2) * R + r] + v3 * Wsc[(size_t)(e0 + 3) * R + r];
        }
        #pragma unroll
        for (int r = 0; r < R; ++r) {
            for (int off = 32; off; off >>= 1) p[r] += __shfl_down(p[r], off, 64);
        }
        if (lane == 0) {
            #pragma unroll
            for (int r = 0; r < R; ++r) sAB[(size_t)rid * R + r] = p[r];
        }
    } else {
        // ---- sent finish + sS for batch b ----
        int b = blk - G3_PROJ;
        __shared__ float sent[H];
        __shared__ float red[R][4];
        for (int h = t; h < H; h += 256) {
            float mx = -INFINITY;
            #pragma unroll 8
            for (int z = 0; z < NZ; ++z) mx = fmaxf(mx, part[((size_t)z * B + b) * H + h]);
            sent[h] = mx;
        }
        __syncthreads();
        float acc[R] = {};
        for (int h = t; h < H; h += 256) {
            float v = sent[h];
            const float* w = Wsc + (size_t)(2 * E + D + h) * R;
            #pragma unroll
            for (int r = 0; r < R; ++r) acc[r] += v * w[r];
        }
        #pragma unroll
        for (int r = 0; r < R; ++r) {
            float v = acc[r];
            for (int off = 32; off; off >>= 1) v += __shfl_down(v, off, 64);
            if (lane == 0) red[r][wave] = v;
        }
        __syncthreads();
        if (t < R) sS[b * R + t] = red[t][0] + red[t][1] + red[t][2] + red[t][3] + bsc[t];
    }
}

// ===========================================================================
// k4: pair-max, tiled.  grid 96, block 256: 8 m-rows x 96 n per block.
// (byte-identical to round 12 — proven)
// ===========================================================================
__global__ __launch_bounds__(256)
void k4(const int* __restrict__ distance,
        const float* __restrict__ sAB, const float* __restrict__ validAB,
        const float* __restrict__ sD, const float* __restrict__ sS,
        float* __restrict__ out) {
    const int g = blockIdx.x % (M / MT4);
    const int b = blockIdx.x / (M / MT4);
    const int t = threadIdx.x;
    const int wave = t >> 6, lane = t & 63;

    __shared__ float lB[M * R];        // 1.9 KB
    __shared__ float lD[MAXD * R];     // 12 KB
    __shared__ float lA[MT4 * R];
    __shared__ float lvA[MT4], lvB[M];
    __shared__ float red[R][4];

    for (int i = t; i < M * R; i += 256) lB[i] = sAB[((size_t)(B + b)) * M * R + i];
    for (int i = t; i < MAXD * R; i += 256) lD[i] = sD[i];
    if (t < MT4 * R) lA[t] = sAB[((size_t)b * M + g * MT4) * R + t] + sS[b * R + (t % R)];
    if (t < MT4) lvA[t] = validAB[(size_t)b * M + g * MT4 + t];
    for (int i = t; i < M; i += 256) lvB[i] = validAB[((size_t)B + b) * M + i];
    __syncthreads();

    float mx[R];
    #pragma unroll
    for (int r = 0; r < R; ++r) mx[r] = NEG_INF;

    #pragma unroll
    for (int it = 0; it < (MT4 * M) / 256; ++it) {
        int idx = it * 256 + t;           // [0, 768)
        int mi = idx / M, n = idx % M;
        int dist = distance[((size_t)b * M + g * MT4 + mi) * M + n];
        if (lvA[mi] > 0.f && lvB[n] > 0.f && dist >= 0 /*DIST_THRESH*/) {
            #pragma unroll
            for (int r = 0; r < R; ++r)
                mx[r] = fmaxf(mx[r], lA[mi * R + r] + lB[n * R + r] + lD[dist * R + r]);
        }
    }
    #pragma unroll
    for (int r = 0; r < R; ++r) {
        float v = mx[r];
        for (int off = 32; off; off >>= 1) v = fmaxf(v, __shfl_down(v, off, 64));
        if (lane == 0) red[r][wave] = v;
    }
    __syncthreads();
    if (t < R) {
        float v = fmaxf(fmaxf(red[t][0], red[t][1]), fmaxf(red[t][2], red[t][3]));
        atomicMaxFloat(out + b * R + t, v);
    }
}

// ---------------------------------------------------------------------------
extern "C" void kernel_launch(void* const* d_in, const int* in_sizes, int n_in,
                              void* d_out, int out_size, void* d_ws, size_t ws_size,
                              hipStream_t stream) {
    const float* node     = (const float*)d_in[0];
    const int*   cmap     = (const int*)  d_in[1];
    const float* cmask    = (const float*)d_in[2];
    const int*   dmap     = (const int*)  d_in[3];
    const float* dmask    = (const float*)d_in[4];
    const int*   distance = (const int*)  d_in[5];
    const float* Wc       = (const float*)d_in[6];
    const float* bc       = (const float*)d_in[7];
    const float* Wd       = (const float*)d_in[8];
    const float* bd       = (const float*)d_in[9];
    const float* Wsc      = (const float*)d_in[10];
    const float* bsc      = (const float*)d_in[11];
    const float* emb      = (const float*)d_in[12];
    float* out = (float*)d_out;

    // workspace layout (floats): total ~7 MB
    float* ws      = (float*)d_ws;
    float* part    = ws;                             // NZ*B*H      = 131072
    float* validAB = part + (size_t)NZ * B * H;      // 2*B*M       = 1536
    float* sD      = validAB + 2 * B * M;            // MAXD*R      = 3000
    float* sS      = sD + MAXD * R;                  // B*R         = 40
    float* sAB     = sS + B * R;                     // RS*R        = 7680
    float* dotp    = sAB + (size_t)RS * R;           // HC*RS*E     = 1572864

    hipLaunchKernelGGL(k1, dim3(G1), dim3(256), 0, stream,
                       node, cmap, cmask, dmap, dmask, Wc, Wd, Wsc, emb,
                       part, dotp, validAB, sD, out);
    hipLaunchKernelGGL(k3, dim3(G3), dim3(256), 0, stream,
                       dotp, bc, bd, Wsc, bsc, part, sAB, sS);
    hipLaunchKernelGGL(k4, dim3((M / MT4) * B), dim3(256), 0, stream,
                       distance, sAB, validAB, sD, sS, out);
}

// Round 19
// 50.358 us; speedup vs baseline: 1.8367x; 1.1502x over previous
//
#include <hip/hip_runtime.h>
#include <math.h>

// Problem constants (from reference setup_inputs)
constexpr int B = 8, N = 2048, H = 512, M = 96, S = 16;
constexpr int E = 256, D = 64, R = 5, MAXD = 600;
constexpr int NZ = 32;            // n-splits for sent max partial
constexpr int NCHUNK = N / NZ;    // 64
constexpr int MT = 8;             // mentions per gemm block
constexpr int HC = 4;             // h-chunks
constexpr int HCH = H / HC;       // 128
constexpr int MT4 = 8;            // m-rows per final-max tile
constexpr int RS = 2 * B * M;     // dotp row-stride (1536 rows)
constexpr float NEG_INF = -1e10f;

constexpr int G_GEMM = 2 * B * (M / MT) * HC;   // 768 pool-slice+partial-gemm blocks
constexpr int G_SENT = B * NZ / 2;              // 128 sent-partial blocks (2 z each)
constexpr int G_DIST = MAXD / 4;                // 150
constexpr int G1 = G_GEMM + G_SENT + G_DIST;    // 1046

constexpr int G3_PROJ = RS / 4;                 // 384 tanh+proj blocks (4 rows each)
constexpr int G3 = G3_PROJ + B;                 // + 8 sS blocks

__device__ inline void atomicMaxFloat(float* addr, float val) {
    int* ai = (int*)addr;
    int old = *ai;
    while (__int_as_float(old) < val) {
        int assumed = old;
        old = atomicCAS(ai, assumed, __float_as_int(val));
        if (old == assumed) break;
    }
}

// ===========================================================================
// k1: fused pool-slice+partial-GEMM | sent-partial max | dist table | out init
// (byte-identical to round 12 — best measured)
// ===========================================================================
__global__ __launch_bounds__(256)
void k1(const float* __restrict__ node,
        const int* __restrict__ cmap, const float* __restrict__ cmask,
        const int* __restrict__ dmap, const float* __restrict__ dmask,
        const float* __restrict__ Wc, const float* __restrict__ Wd,
        const float* __restrict__ Wsc, const float* __restrict__ emb,
        float* __restrict__ part, float* __restrict__ dotp,
        float* __restrict__ validAB, float* __restrict__ sD,
        float* __restrict__ out) {
    const int blk = blockIdx.x;
    const int t = threadIdx.x;

    if (blk == 0 && t < B * R) out[t] = NEG_INF;   // init for k4's atomicMax

    if (blk < G_GEMM) {
        // block = (z, b, mg, hc): pool h-slice for 8 mentions, partial GEMM
        int hc   = blk & 3;
        int rest = blk >> 2;
        int mg = rest % (M / MT);
        int b  = (rest / (M / MT)) % B;
        int z  = rest / ((M / MT) * B);
        const float* W    = z ? Wd : Wc;
        const int*   map  = z ? dmap  : cmap;
        const float* mask = z ? dmask : cmask;

        __shared__ int   smap[MT][S];
        __shared__ float smask[MT][S];
        __shared__ float lp[MT][HCH];      // 4 KB

        if (t < MT * S) {
            int mi = t >> 4, s = t & 15;
            size_t off = ((size_t)b * M + mg * MT + mi) * S + s;
            smap[mi][s]  = map[off];
            smask[mi][s] = mask[off];
        }
        __syncthreads();

        // pool slice: thread = (mention, float4-slot of 128-h slice)
        {
            int mi = t >> 5, slot = t & 31;
            float4 a = make_float4(0.f, 0.f, 0.f, 0.f);
            #pragma unroll
            for (int s = 0; s < S; ++s) {
                float mk = smask[mi][s];
                const float4 v = reinterpret_cast<const float4*>(
                    node + ((size_t)b * N + smap[mi][s]) * H + hc * HCH)[slot];
                a.x += mk * v.x; a.y += mk * v.y;
                a.z += mk * v.z; a.w += mk * v.w;
            }
            reinterpret_cast<float4*>(&lp[mi][0])[slot] = a;
        }
        if (hc == 0 && t < MT) {
            float ms = 0.f;
            #pragma unroll
            for (int s = 0; s < S; ++s) ms += smask[t][s];
            validAB[((size_t)z * B + b) * M + mg * MT + t] = (ms > 0.f) ? 1.f : 0.f;
        }
        __syncthreads();

        // partial GEMM: thread = e; W rows coalesced across threads
        float acc[MT] = {};
        const float* Wp = W + (size_t)(hc * HCH) * E + t;
        #pragma unroll 4
        for (int hh = 0; hh < HCH; hh += 4) {
            float w0 = Wp[(size_t)(hh + 0) * E];
            float w1 = Wp[(size_t)(hh + 1) * E];
            float w2 = Wp[(size_t)(hh + 2) * E];
            float w3 = Wp[(size_t)(hh + 3) * E];
            #pragma unroll
            for (int mi = 0; mi < MT; ++mi) {
                const float4 pv = *reinterpret_cast<const float4*>(&lp[mi][hh]);
                acc[mi] += pv.x * w0 + pv.y * w1 + pv.z * w2 + pv.w * w3;
            }
        }
        #pragma unroll
        for (int mi = 0; mi < MT; ++mi) {
            size_t row = ((size_t)z * B + b) * M + mg * MT + mi;
            dotp[((size_t)hc * RS + row) * E + t] = acc[mi];
        }
    } else if (blk < G_GEMM + G_SENT) {
        // sent partial max: block = (b, 2 z-chunks); z-chunk = 64 tokens
        int sb = blk - G_GEMM;
        int b = sb >> 4;
        int z = ((sb & 15) << 1) + (t >> 7);
        int tt = t & 127;   // float4 index over H
        const float4* p = reinterpret_cast<const float4*>(
            node + ((size_t)b * N + (size_t)z * NCHUNK) * H) + tt;
        float4 mx = p[0];
        #pragma unroll 8
        for (int n = 1; n < NCHUNK; ++n) {
            float4 v = p[(size_t)n * (H / 4)];
            mx.x = fmaxf(mx.x, v.x); mx.y = fmaxf(mx.y, v.y);
            mx.z = fmaxf(mx.z, v.z); mx.w = fmaxf(mx.w, v.w);
        }
        reinterpret_cast<float4*>(part + ((size_t)z * B + b) * H)[tt] = mx;
    } else {
        // distance table: 4 distances per block, one wave each
        int d = (blk - G_GEMM - G_SENT) * 4 + (t >> 6);
        int k = t & 63;
        float v = emb[(size_t)d * D + k];
        #pragma unroll
        for (int r = 0; r < R; ++r) {
            float p = v * Wsc[(size_t)(2 * E + k) * R + r];
            for (int off = 32; off; off >>= 1) p += __shfl_down(p, off, 64);
            if (k == 0) sD[d * R + r] = p;
        }
    }
}

// ===========================================================================
// k3: tanh+proj per entity row (blocks [0,384), wave = row) | sent sS ([384,392))
// ===========================================================================
__global__ __launch_bounds__(256)
void k3(const float* __restrict__ dotp,
        const float* __restrict__ bc, const float* __restrict__ bd,
        const float* __restrict__ Wsc, const float* __restrict__ bsc,
        const float* __restrict__ part,
        float* __restrict__ sAB, float* __restrict__ sS) {
    const int blk = blockIdx.x;
    const int t = threadIdx.x;
    const int wave = t >> 6, lane = t & 63;

    if (blk < G3_PROJ) {
        int rid = blk * 4 + wave;            // entity row in [0, 1536)
        int z = rid / (B * M);
        const float* bias = z ? bd : bc;
        int scoff = z ? E : 0;

        // sum 4 h-chunk partials + bias (float4 over E, lane = e-quad)
        float4 dv = reinterpret_cast<const float4*>(bias)[lane];
        #pragma unroll
        for (int hc = 0; hc < HC; ++hc) {
            const float4 v = reinterpret_cast<const float4*>(
                dotp + ((size_t)hc * RS + rid) * E)[lane];
            dv.x += v.x; dv.y += v.y; dv.z += v.z; dv.w += v.w;
        }
        float v0 = tanhf(dv.x), v1 = tanhf(dv.y), v2 = tanhf(dv.z), v3 = tanhf(dv.w);

        int e0 = scoff + 4 * lane;
        float p[R];
        #pragma unroll
        for (int r = 0; r < R; ++r) {
            p[r] = v0 * Wsc[(size_t)(e0 + 0) * R + r] + v1 * Wsc[(size_t)(e0 + 1) * R + r]
                 + v2 * Wsc[(size_t)(e0 + 2) * R + r] + v3 * Wsc[(size_t)(e0 + 3) * R + r];
        }
        #pragma unroll
        for (int r = 0; r < R; ++r) {
            for (int off = 32; off; off >>= 1) p[r] += __shfl_down(p[r], off, 64);
        }
        if (lane == 0) {
            #pragma unroll
            for (int r = 0; r < R; ++r) sAB[(size_t)rid * R + r] = p[r];
        }
    } else {
        // ---- sent finish + sS for batch b ----
        int b = blk - G3_PROJ;
        __shared__ float sent[H];
        __shared__ float red[R][4];
        for (int h = t; h < H; h += 256) {
            float mx = -INFINITY;
            #pragma unroll 8
            for (int z = 0; z < NZ; ++z) mx = fmaxf(mx, part[((size_t)z * B + b) * H + h]);
            sent[h] = mx;
        }
        __syncthreads();
        float acc[R] = {};
        for (int h = t; h < H; h += 256) {
            float v = sent[h];
            const float* w = Wsc + (size_t)(2 * E + D + h) * R;
            #pragma unroll
            for (int r = 0; r < R; ++r) acc[r] += v * w[r];
        }
        #pragma unroll
        for (int r = 0; r < R; ++r) {
            float v = acc[r];
            for (int off = 32; off; off >>= 1) v += __shfl_down(v, off, 64);
            if (lane == 0) red[r][wave] = v;
        }
        __syncthreads();
        if (t < R) sS[b * R + t] = red[t][0] + red[t][1] + red[t][2] + red[t][3] + bsc[t];
    }
}

// ===========================================================================
// k4: pair-max, tiled.  grid 96, block 256: 8 m-rows x 96 n per block.
// ===========================================================================
__global__ __launch_bounds__(256)
void k4(const int* __restrict__ distance,
        const float* __restrict__ sAB, const float* __restrict__ validAB,
        const float* __restrict__ sD, const float* __restrict__ sS,
        float* __restrict__ out) {
    const int g = blockIdx.x % (M / MT4);
    const int b = blockIdx.x / (M / MT4);
    const int t = threadIdx.x;
    const int wave = t >> 6, lane = t & 63;

    __shared__ float lB[M * R];        // 1.9 KB
    __shared__ float lD[MAXD * R];     // 12 KB
    __shared__ float lA[MT4 * R];
    __shared__ float lvA[MT4], lvB[M];
    __shared__ float red[R][4];

    for (int i = t; i < M * R; i += 256) lB[i] = sAB[((size_t)(B + b)) * M * R + i];
    for (int i = t; i < MAXD * R; i += 256) lD[i] = sD[i];
    if (t < MT4 * R) lA[t] = sAB[((size_t)b * M + g * MT4) * R + t] + sS[b * R + (t % R)];
    if (t < MT4) lvA[t] = validAB[(size_t)b * M + g * MT4 + t];
    for (int i = t; i < M; i += 256) lvB[i] = validAB[((size_t)B + b) * M + i];
    __syncthreads();

    float mx[R];
    #pragma unroll
    for (int r = 0; r < R; ++r) mx[r] = NEG_INF;

    #pragma unroll
    for (int it = 0; it < (MT4 * M) / 256; ++it) {
        int idx = it * 256 + t;           // [0, 768)
        int mi = idx / M, n = idx % M;
        int dist = distance[((size_t)b * M + g * MT4 + mi) * M + n];
        if (lvA[mi] > 0.f && lvB[n] > 0.f && dist >= 0 /*DIST_THRESH*/) {
            #pragma unroll
            for (int r = 0; r < R; ++r)
                mx[r] = fmaxf(mx[r], lA[mi * R + r] + lB[n * R + r] + lD[dist * R + r]);
        }
    }
    #pragma unroll
    for (int r = 0; r < R; ++r) {
        float v = mx[r];
        for (int off = 32; off; off >>= 1) v = fmaxf(v, __shfl_down(v, off, 64));
        if (lane == 0) red[r][wave] = v;
    }
    __syncthreads();
    if (t < R) {
        float v = fmaxf(fmaxf(red[t][0], red[t][1]), fmaxf(red[t][2], red[t][3]));
        atomicMaxFloat(out + b * R + t, v);
    }
}

// ---------------------------------------------------------------------------
extern "C" void kernel_launch(void* const* d_in, const int* in_sizes, int n_in,
                              void* d_out, int out_size, void* d_ws, size_t ws_size,
                              hipStream_t stream) {
    const float* node     = (const float*)d_in[0];
    const int*   cmap     = (const int*)  d_in[1];
    const float* cmask    = (const float*)d_in[2];
    const int*   dmap     = (const int*)  d_in[3];
    const float* dmask    = (const float*)d_in[4];
    const int*   distance = (const int*)  d_in[5];
    const float* Wc       = (const float*)d_in[6];
    const float* bc       = (const float*)d_in[7];
    const float* Wd       = (const float*)d_in[8];
    const float* bd       = (const float*)d_in[9];
    const float* Wsc      = (const float*)d_in[10];
    const float* bsc      = (const float*)d_in[11];
    const float* emb      = (const float*)d_in[12];
    float* out = (float*)d_out;

    // workspace layout (floats): total ~7 MB
    float* ws      = (float*)d_ws;
    float* part    = ws;                             // NZ*B*H      = 131072
    float* validAB = part + (size_t)NZ * B * H;      // 2*B*M       = 1536
    float* sD      = validAB + 2 * B * M;            // MAXD*R      = 3000
    float* sS      = sD + MAXD * R;                  // B*R         = 40
    float* sAB     = sS + B * R;                     // RS*R        = 7680
    float* dotp    = sAB + (size_t)RS * R;           // HC*RS*E     = 1572864

    hipLaunchKernelGGL(k1, dim3(G1), dim3(256), 0, stream,
                       node, cmap, cmask, dmap, dmask, Wc, Wd, Wsc, emb,
                       part, dotp, validAB, sD, out);
    hipLaunchKernelGGL(k3, dim3(G3), dim3(256), 0, stream,
                       dotp, bc, bd, Wsc, bsc, part, sAB, sS);
    hipLaunchKernelGGL(k4, dim3((M / MT4) * B), dim3(256), 0, stream,
                       distance, sAB, validAB, sD, sS, out);
}